// Round 2
// baseline (28727.036 us; speedup 1.0000x reference)
//
#include <hip/hip_runtime.h>
#include <hip/hip_bf16.h>

// ---------------------------------------------------------------------------
// BayesianFilter: graph-GRU recurrent net.
// Key trick: gconv(xe_t) is linear in x_t, so edge aggregation is done ONCE in
// C-space (16 dims) for all t (k_agg), and the fused weight W_eg = W_enc@W_gX
// turns the per-step gconv into a row-local 16->64 matmul. After that the
// whole recurrence is row-parallel: one persistent kernel, no grid syncs.
//
// Round 2: runtime input-dtype detection (f32 vs bf16). Reading f32 buffers as
// bf16 halves produces 1e38-scale garbage -> inf-inf -> NaN (round-1 failure
// signature). k_detect writes a flag to ws; all loads/stores branch on it.
// ---------------------------------------------------------------------------

typedef unsigned short u16;

constexpr int N_ = 8, V_ = 2048, C_ = 16, T_ = 150, L_ = 64, E_ = 32768;
constexpr int NV_ = N_ * V_;             // 16384 rows
constexpr int CT_ = C_ * T_;             // 2400

// ---- workspace layout (bytes) ----
constexpr size_t SZ_AGGT   = (size_t)T_ * N_ * V_ * C_ * 2;     // 78,643,200 bf16
constexpr size_t OFF_AGGT  = 0;
constexpr size_t OFF_COUNTS= OFF_AGGT + SZ_AGGT;                // int[V]
constexpr size_t OFF_S     = OFF_COUNTS + 8192;                 // float[V]
constexpr size_t OFF_RP    = OFF_S + 8192;                      // int[V+1] (pad)
constexpr size_t OFF_CUR   = OFF_RP + 8448;                     // int[V]
constexpr size_t OFF_CSRC  = OFF_CUR + 8192;                    // int[E]
constexpr size_t OFF_CATT  = OFF_CSRC + 131072;                 // float[E]
constexpr size_t OFF_WEGA  = OFF_CATT + 131072;                 // bf16[16][64]
constexpr size_t OFF_WEGB  = OFF_WEGA + 2048;
constexpr size_t OFF_BEGA  = OFF_WEGB + 2048;                   // float[64]
constexpr size_t OFF_BEGB  = OFF_BEGA + 256;
constexpr size_t OFF_FLAG  = OFF_BEGB + 256;                    // int dtype flag
constexpr size_t OFF_STAGE = OFF_FLAG + 256;                    // bf16 [T][NV][C]
constexpr size_t NEED_STAGE= OFF_STAGE + SZ_AGGT;               // ~157.6 MB

// ---- mega-kernel LDS layout (bytes). pitches chosen for <=2-way banks ----
constexpr int PITCH = 68;   // ushorts; row stride 136B -> bank stride 34 -> 2-way
constexpr int PEG   = 20;   // ushorts; 40B -> 10 dwords -> 2-way
constexpr int L_WIT = 0;                  // [192][68] bf16 = 26112
constexpr int L_WHT = 26112;              // 26112
constexpr int L_W1H = 52224;              // [64][68]  = 8704
constexpr int L_W2  = 60928;              // 8704
constexpr int L_WDEC= 69632;              // [16][68]  = 2176
constexpr int L_WEG = 71808;              // [64][20]  = 2560
constexpr int L_FB  = 74368;              // float[336] (pad 1408)
constexpr int L_H   = 75776;              // bf16[16][64] = 2048
constexpr int L_M   = 77824;              // 2048
constexpr int L_AGG = 79872;              // bf16[16][16] = 512
constexpr int L_S   = 80384;              // float[16]
constexpr int LDS_MEGA = 80448;           // <= 81920 -> 2 blocks/CU

#define DEVI __device__ __forceinline__

DEVI float bf2f(u16 u) {
    unsigned int v = ((unsigned int)u) << 16;
    float f; __builtin_memcpy(&f, &v, 4); return f;
}
DEVI u16 f2bf(float f) {   // round-to-nearest-even
    unsigned int v; __builtin_memcpy(&v, &f, 4);
    unsigned int r = (v + 0x7fffu + ((v >> 16) & 1u)) >> 16;
    return (u16)r;
}
// dtype-flag-aware scalar load: element i of a float32 OR bf16 buffer
DEVI float ldf(const void* p, size_t i, int f32) {
    return f32 ? ((const float*)p)[i] : bf2f(((const u16*)p)[i]);
}
DEVI float4 bf4(const u16* p) {
    ushort4 u = *reinterpret_cast<const ushort4*>(p);
    return make_float4(bf2f(u.x), bf2f(u.y), bf2f(u.z), bf2f(u.w));
}
DEVI float dot4(float4 a, float4 b) {
    return a.x*b.x + a.y*b.y + a.z*b.z + a.w*b.w;
}
DEVI float sigm(float v) { return 1.f / (1.f + __expf(-v)); }
DEVI float tanh_(float v) {   // overflow-safe tanh via exp of -2|x|
    float a = fabsf(v);
    float e = __expf(-2.f * a);
    float t = (1.f - e) / (1.f + e);
    return v < 0.f ? -t : t;
}

// transposed weight loads into LDS: dst[o*pitch + k] = src[k*O + o]
DEVI void loadT64(u16* dst, const void* src, int O, int pitch, int f32) {
    for (int i = threadIdx.x; i < 64 * O; i += 256) {
        int o = i >> 6, k = i & 63;
        dst[o * pitch + k] = f2bf(ldf(src, (size_t)k * O + o, f32));
    }
}
DEVI void loadT16(u16* dst, const void* src, int O, int pitch, int f32) {
    for (int i = threadIdx.x; i < 16 * O; i += 256) {
        int o = i >> 4, k = i & 15;
        dst[o * pitch + k] = f2bf(ldf(src, (size_t)k * O + o, f32));
    }
}
DEVI void loadBias(float* dst, const void* src, int n, int f32) {
    for (int i = threadIdx.x; i < n; i += 256) dst[i] = ldf(src, i, f32);
}

// out[16 x 64] += act[16 x 64] @ W[64 x 64]   (WT layout [o][k], per-thread 4 rows)
DEVI void gemm64(const u16* WT, const u16* act, int l, int rb,
                 const float init[4], float out[4]) {
    const u16* w  = WT + l * PITCH;
    const u16* a0 = act + (rb +  0) * 64;
    const u16* a1 = act + (rb +  4) * 64;
    const u16* a2 = act + (rb +  8) * 64;
    const u16* a3 = act + (rb + 12) * 64;
    float o0 = init[0], o1 = init[1], o2 = init[2], o3 = init[3];
#pragma unroll
    for (int k4 = 0; k4 < 16; ++k4) {
        float4 wv = bf4(w + 4 * k4);
        o0 += dot4(bf4(a0 + 4 * k4), wv);
        o1 += dot4(bf4(a1 + 4 * k4), wv);
        o2 += dot4(bf4(a2 + 4 * k4), wv);
        o3 += dot4(bf4(a3 + 4 * k4), wv);
    }
    out[0] = o0; out[1] = o1; out[2] = o2; out[3] = o3;
}

// fused GRU gate GEMMs: gi = m@Wi + b, gh = h@Wh ; z/r summed, n parts separate
DEVI void gruGemm(const u16* WiT, const u16* WhT, const u16* mS, const u16* hS,
                  int l, int rb, const float* bg,
                  float az[4], float ar[4], float ani[4], float anh[4]) {
#pragma unroll
    for (int j = 0; j < 4; ++j) {
        az[j] = bg[l]; ar[j] = bg[64 + l]; ani[j] = bg[128 + l]; anh[j] = 0.f;
    }
    const u16* wz = WiT + (  0 + l) * PITCH;
    const u16* wr = WiT + ( 64 + l) * PITCH;
    const u16* wn = WiT + (128 + l) * PITCH;
    const u16* vz = WhT + (  0 + l) * PITCH;
    const u16* vr = WhT + ( 64 + l) * PITCH;
    const u16* vn = WhT + (128 + l) * PITCH;
#pragma unroll
    for (int k4 = 0; k4 < 16; ++k4) {
        float4 a = bf4(wz + 4*k4), b = bf4(wr + 4*k4), c = bf4(wn + 4*k4);
        float4 d = bf4(vz + 4*k4), e = bf4(vr + 4*k4), f = bf4(vn + 4*k4);
#pragma unroll
        for (int j = 0; j < 4; ++j) {
            int r = rb + 4 * j;
            float4 mm = bf4(mS + r * 64 + 4 * k4);
            float4 hh = bf4(hS + r * 64 + 4 * k4);
            az[j]  += dot4(mm, a) + dot4(hh, d);
            ar[j]  += dot4(mm, b) + dot4(hh, e);
            ani[j] += dot4(mm, c);
            anh[j] += dot4(hh, f);
        }
    }
}

// m = agg_c @ W_eg + S * b_eg  -> mS (bf16)
DEVI void mcalc(const u16* WegT, const u16* aggS, const float* beg,
                const float* Sl, int l, int rb, u16* mS) {
    const u16* w = WegT + l * PEG;
    float4 w0 = bf4(w), w1 = bf4(w + 4), w2 = bf4(w + 8), w3 = bf4(w + 12);
#pragma unroll
    for (int j = 0; j < 4; ++j) {
        int r = rb + 4 * j;
        float acc = Sl[r] * beg[l];
        acc += dot4(bf4(aggS + r*16     ), w0) + dot4(bf4(aggS + r*16 +  4), w1)
             + dot4(bf4(aggS + r*16 +  8), w2) + dot4(bf4(aggS + r*16 + 12), w3);
        mS[r * 64 + l] = f2bf(acc);
    }
}

DEVI void decodeStore(const u16* WdT, const u16* hS, const float* bd,
                      int rg, int cg, void* outp, int staged, int isf32,
                      int base, int t) {
    float acc = bd[cg];
    const u16* w = WdT + cg * PITCH;
    const u16* a = hS + rg * 64;
#pragma unroll
    for (int k4 = 0; k4 < 16; ++k4) acc += dot4(bf4(w + 4*k4), bf4(a + 4*k4));
    if (staged) {
        ((u16*)outp)[((size_t)t * NV_ + base + rg) * C_ + cg] = f2bf(acc);
    } else {
        size_t off = (size_t)(base + rg) * CT_ + (size_t)cg * T_ + t;
        if (isf32) ((float*)outp)[off] = acc;
        else       ((u16*)outp)[off] = f2bf(acc);
    }
}

// ---------------------------------------------------------------------------
// dtype detection: interpret first 1024 u16 of x as bf16. True bf16 N(0,1)
// data has exponent field <= ~0x81. f32 data misread as bf16 gives ~40% of
// the low-half u16s an exponent >= 0x9A (|v| >= 2^27). Count >= 8 -> f32.
// ---------------------------------------------------------------------------
__global__ void k_detect(const u16* __restrict__ x, int* __restrict__ flag) {
    __shared__ int cnt;
    if (threadIdx.x == 0) cnt = 0;
    __syncthreads();
    int local = 0;
#pragma unroll
    for (int j = 0; j < 4; ++j) {
        u16 u = x[threadIdx.x * 4 + j];
        int ex = (u >> 7) & 0xFF;
        if (ex >= 0x9A) ++local;
    }
    if (local) atomicAdd(&cnt, local);
    __syncthreads();
    if (threadIdx.x == 0) *flag = (cnt >= 8) ? 1 : 0;
}

// ---------------------------------------------------------------------------
// CSR build
// ---------------------------------------------------------------------------
__global__ void k_count(const int* __restrict__ ei, const void* __restrict__ eattr,
                        const int* __restrict__ flag,
                        int* __restrict__ counts, float* __restrict__ S) {
    int f32 = *flag;
    int e = blockIdx.x * 256 + threadIdx.x;
    if (e < E_) {
        int dst = ei[E_ + e];
        atomicAdd(&counts[dst], 1);
        atomicAdd(&S[dst], ldf(eattr, e, f32));
    }
}

__global__ void k_scan(const int* __restrict__ counts, int* __restrict__ row_ptr,
                       int* __restrict__ cursor) {
    __shared__ int lds[256];
    int tid = threadIdx.x;
    int base = tid * 8, loc[8], s = 0;
#pragma unroll
    for (int i = 0; i < 8; ++i) { loc[i] = s; s += counts[base + i]; }
    lds[tid] = s; __syncthreads();
    for (int d = 1; d < 256; d <<= 1) {
        int v = (tid >= d) ? lds[tid - d] : 0;
        __syncthreads();
        lds[tid] += v;
        __syncthreads();
    }
    int off = (tid == 0) ? 0 : lds[tid - 1];
#pragma unroll
    for (int i = 0; i < 8; ++i) {
        int rp = off + loc[i];
        row_ptr[base + i] = rp; cursor[base + i] = rp;
    }
    if (tid == 255) row_ptr[V_] = lds[255];
}

__global__ void k_fill(const int* __restrict__ ei, const void* __restrict__ eattr,
                       const int* __restrict__ flag,
                       int* __restrict__ cursor, int* __restrict__ col_src,
                       float* __restrict__ col_att) {
    int f32 = *flag;
    int e = blockIdx.x * 256 + threadIdx.x;
    if (e < E_) {
        int dst = ei[E_ + e];
        int pos = atomicAdd(&cursor[dst], 1);
        col_src[pos] = ei[e];
        col_att[pos] = ldf(eattr, e, f32);
    }
}

// fused weights: W_egX = W_enc @ W_gX ; b_egX = b_enc @ W_gX
__global__ void k_wprep(const void* __restrict__ W_enc, const void* __restrict__ b_enc,
                        const void* __restrict__ W_gd, const void* __restrict__ W_gc,
                        const int* __restrict__ flag,
                        u16* __restrict__ wegA, u16* __restrict__ wegB,
                        float* __restrict__ begA, float* __restrict__ begB) {
    int f32 = *flag;
    int tid = threadIdx.x;
    for (int idx = tid; idx < 1024; idx += 256) {
        int c = idx >> 6, l = idx & 63;
        float sa = 0.f, sb = 0.f;
        for (int k = 0; k < 64; ++k) {
            float we = ldf(W_enc, c * 64 + k, f32);
            sa += we * ldf(W_gd, k * 64 + l, f32);
            sb += we * ldf(W_gc, k * 64 + l, f32);
        }
        wegA[idx] = f2bf(sa); wegB[idx] = f2bf(sb);
    }
    if (tid < 64) {
        float sa = 0.f, sb = 0.f;
        for (int k = 0; k < 64; ++k) {
            float be = ldf(b_enc, k, f32);
            sa += be * ldf(W_gd, k * 64 + tid, f32);
            sb += be * ldf(W_gc, k * 64 + tid, f32);
        }
        begA[tid] = sa; begB[tid] = sb;
    }
}

// ---------------------------------------------------------------------------
// pre-aggregation: aggT[t][n][v][c] = sum_{e: dst=v} attr_e * x[n, src_e, c, t]
// block = (n, 4 dst nodes); x rows are contiguous (c,t) slabs -> coalesced.
// ---------------------------------------------------------------------------
__global__ __launch_bounds__(256) void k_agg(
    const void* __restrict__ x, const int* __restrict__ flag,
    const int* __restrict__ row_ptr,
    const int* __restrict__ col_src, const float* __restrict__ col_att,
    u16* __restrict__ aggT) {
    __shared__ float lbuf[4 * CT_];   // 38,400 B
    int f32 = *flag;
    int tid = threadIdx.x;
    int n  = blockIdx.x >> 9;
    int v0 = (blockIdx.x & 511) * 4;
    for (int d = 0; d < 4; ++d) {
        int v = v0 + d;
        int e0 = row_ptr[v], e1 = row_ptr[v + 1];
        float acc[10];
#pragma unroll
        for (int k = 0; k < 10; ++k) acc[k] = 0.f;
        for (int e = e0; e < e1; ++e) {
            float a = col_att[e];
            size_t ro = (size_t)(n * V_ + col_src[e]) * CT_;
            if (f32) {
                const float* xr = (const float*)x + ro;
#pragma unroll
                for (int k = 0; k < 10; ++k) {
                    int idx = tid + 256 * k;
                    if (idx < CT_) acc[k] += a * xr[idx];
                }
            } else {
                const u16* xr = (const u16*)x + ro;
#pragma unroll
                for (int k = 0; k < 10; ++k) {
                    int idx = tid + 256 * k;
                    if (idx < CT_) acc[k] += a * bf2f(xr[idx]);
                }
            }
        }
#pragma unroll
        for (int k = 0; k < 10; ++k) {
            int idx = tid + 256 * k;
            if (idx < CT_) lbuf[d * CT_ + idx] = acc[k];
        }
    }
    __syncthreads();
    // write in [t][n][v][c] order (128B contiguous per t)
    for (int w = tid; w < 4 * CT_; w += 256) {
        int t = w >> 6, rem = w & 63, d = rem >> 4, c = rem & 15;
        aggT[((size_t)(t * N_ + n) * V_ + v0 + d) * C_ + c] =
            f2bf(lbuf[d * CT_ + c * T_ + t]);
    }
}

// ---------------------------------------------------------------------------
// mega kernel: phase A (domain GRU, 150 steps) -> dom MLP + zdterm ->
// phase B (ODE + GRU + decode, steps 1..149). 16 rows / block, all row-local.
// thread maps: (l = tid&63, rows rb+4j) for GEMMs; (rg = tid>>4, cg = tid&15)
// for agg/x0/decode.
// ---------------------------------------------------------------------------
__global__ __launch_bounds__(256, 2) void k_mega(
    const void* __restrict__ x, const u16* __restrict__ aggT,
    const float* __restrict__ Sg, const int* __restrict__ flag,
    const void* __restrict__ W_enc, const void* __restrict__ b_enc,
    const void* __restrict__ gd_Wi, const void* __restrict__ gd_Wh, const void* __restrict__ gd_b,
    const void* __restrict__ W_dom1, const void* __restrict__ b_dom1,
    const void* __restrict__ W_dom2, const void* __restrict__ b_dom2,
    const void* __restrict__ ode_W1, const void* __restrict__ ode_b1,
    const void* __restrict__ ode_W2, const void* __restrict__ ode_b2,
    const void* __restrict__ gc_Wi, const void* __restrict__ gc_Wh, const void* __restrict__ gc_b,
    const void* __restrict__ W_dec, const void* __restrict__ b_dec,
    const u16* __restrict__ wegA, const u16* __restrict__ wegB,
    const float* __restrict__ begA, const float* __restrict__ begB,
    void* __restrict__ outp, int staged) {
    extern __shared__ char smem[];
    u16* WiT  = (u16*)(smem + L_WIT);
    u16* WhT  = (u16*)(smem + L_WHT);
    u16* W1hT = (u16*)(smem + L_W1H);
    u16* W2T  = (u16*)(smem + L_W2);
    u16* WdT  = (u16*)(smem + L_WDEC);
    u16* WegT = (u16*)(smem + L_WEG);
    float* fB = (float*)(smem + L_FB);    // [0..191] gate bias, [192..255] b_eg,
                                          // [256..319] ode_b2, [320..335] b_dec
    u16* hS   = (u16*)(smem + L_H);
    u16* mS   = (u16*)(smem + L_M);
    u16* aggS = (u16*)(smem + L_AGG);
    float* Sl = (float*)(smem + L_S);

    const int f32 = *flag;
    const int tid = threadIdx.x;
    const int l = tid & 63, rb = tid >> 6;
    const int rg = tid >> 4, cg = tid & 15;
    const int base = blockIdx.x * 16;
    const int n = base >> 11, v0 = base & 2047;

    // ---- phase A setup
    loadT64(WiT, gd_Wi, 192, PITCH, f32);
    loadT64(WhT, gd_Wh, 192, PITCH, f32);
    for (int i = tid; i < 16 * 64; i += 256) {     // wegA already bf16
        int o = i >> 4, k = i & 15;
        WegT[o * PEG + k] = wegA[k * 64 + o];
    }
    loadBias(fB, gd_b, 192, f32);
    for (int i = tid; i < 64; i += 256) fB[192 + i] = begA[i];
    if (tid < 16) Sl[tid] = Sg[v0 + tid];
    __syncthreads();

    float hd[4] = {0.f, 0.f, 0.f, 0.f};
    for (int t = 0; t < T_; ++t) {
        aggS[tid] = aggT[((size_t)(t * N_ + n) * V_ + v0) * C_ + tid];
#pragma unroll
        for (int j = 0; j < 4; ++j) hS[(rb + 4*j) * 64 + l] = f2bf(hd[j]);
        __syncthreads();
        mcalc(WegT, aggS, fB + 192, Sl, l, rb, mS);
        __syncthreads();
        float az[4], ar[4], ani[4], anh[4];
        gruGemm(WiT, WhT, mS, hS, l, rb, fB, az, ar, ani, anh);
#pragma unroll
        for (int j = 0; j < 4; ++j) {
            float z = sigm(az[j]);
            float r = sigm(ar[j]);
            float nn = tanh_(ani[j] + r * anh[j]);
            hd[j] = (1.f - z) * nn + z * hd[j];
        }
        __syncthreads();
    }

    // ---- domain MLP: z_D = tanh(hd@Wdom1+b1)@Wdom2+b2 ; zdterm = zD@W1[64:]+ode_b1
#pragma unroll
    for (int j = 0; j < 4; ++j) hS[(rb + 4*j) * 64 + l] = f2bf(hd[j]);
    loadT64(W1hT, W_dom1, 64, PITCH, f32);
    loadT64(W2T,  W_dom2, 64, PITCH, f32);
    loadT64(WiT,  (const void*)((const char*)ode_W1 + (size_t)64 * 64 * (f32 ? 4 : 2)),
            64, PITCH, f32);   // zD half of ode_W1
    loadBias(fB,       b_dom1, 64, f32);
    loadBias(fB + 64,  b_dom2, 64, f32);
    loadBias(fB + 128, ode_b1, 64, f32);
    __syncthreads();
    float init4[4], tmp4[4];
#pragma unroll
    for (int j = 0; j < 4; ++j) init4[j] = fB[l];
    gemm64(W1hT, hS, l, rb, init4, tmp4);
#pragma unroll
    for (int j = 0; j < 4; ++j) mS[(rb + 4*j) * 64 + l] = f2bf(tanh_(tmp4[j]));
    __syncthreads();
    float zD[4];
#pragma unroll
    for (int j = 0; j < 4; ++j) init4[j] = fB[64 + l];
    gemm64(W2T, mS, l, rb, init4, zD);
    __syncthreads();
#pragma unroll
    for (int j = 0; j < 4; ++j) hS[(rb + 4*j) * 64 + l] = f2bf(zD[j]);
    __syncthreads();
    float zt[4];
#pragma unroll
    for (int j = 0; j < 4; ++j) init4[j] = fB[128 + l];
    gemm64(WiT, hS, l, rb, init4, zt);
    __syncthreads();

    // ---- phase B setup
    loadT64(WiT, gc_Wi, 192, PITCH, f32);
    loadT64(WhT, gc_Wh, 192, PITCH, f32);
    loadT64(W1hT, ode_W1, 64, PITCH, f32);   // h half
    loadT64(W2T,  ode_W2, 64, PITCH, f32);
    loadT64(WdT,  W_dec, 16, PITCH, f32);
    loadT16(WegT, W_enc, 64, PEG, f32);      // raw W_enc for h0
    loadBias(fB, b_enc, 64, f32);
    loadBias(fB + 256, ode_b2, 64, f32);
    loadBias(fB + 320, b_dec, 16, f32);
    for (int i = tid; i < 64; i += 256) fB[192 + i] = begB[i];
    __syncthreads();
    // h0 = x[:,:,:,0] @ W_enc + b_enc
    aggS[tid] = f2bf(ldf(x, (size_t)(base + rg) * CT_ + (size_t)cg * T_, f32));
    __syncthreads();
    float h[4];
    {
        const u16* w = WegT + l * PEG;
        float4 w0 = bf4(w), w1 = bf4(w+4), w2 = bf4(w+8), w3 = bf4(w+12);
#pragma unroll
        for (int j = 0; j < 4; ++j) {
            int r = rb + 4 * j;
            float acc = fB[l];
            acc += dot4(bf4(aggS + r*16), w0) + dot4(bf4(aggS + r*16 + 4), w1)
                 + dot4(bf4(aggS + r*16 + 8), w2) + dot4(bf4(aggS + r*16 + 12), w3);
            h[j] = acc;
            hS[r * 64 + l] = f2bf(acc);
        }
    }
    __syncthreads();
    decodeStore(WdT, hS, fB + 320, rg, cg, outp, staged, f32, base, 0);
    for (int i = tid; i < 16 * 64; i += 256) {     // wegB already bf16
        int o = i >> 4, k = i & 15;
        WegT[o * PEG + k] = wegB[k * 64 + o];
    }
    loadBias(fB, gc_b, 192, f32);
    __syncthreads();

    for (int t = 1; t < T_; ++t) {
        // s1: agg load + ODE hidden u = tanh(h@W1h + zdterm)
        aggS[tid] = aggT[((size_t)(t * N_ + n) * V_ + v0) * C_ + tid];
        float u[4];
        gemm64(W1hT, hS, l, rb, zt, u);
#pragma unroll
        for (int j = 0; j < 4; ++j) mS[(rb + 4*j) * 64 + l] = f2bf(tanh_(u[j]));
        __syncthreads();
        // s2: dh = u@W2 + b2 ; h_ode = h + dh
        float dh[4];
#pragma unroll
        for (int j = 0; j < 4; ++j) init4[j] = fB[256 + l];
        gemm64(W2T, mS, l, rb, init4, dh);
        float ho[4];
#pragma unroll
        for (int j = 0; j < 4; ++j) ho[j] = h[j] + dh[j];
        __syncthreads();
        // s3: stage h_ode ; m = agg@W_eg + S*b_eg
#pragma unroll
        for (int j = 0; j < 4; ++j) hS[(rb + 4*j) * 64 + l] = f2bf(ho[j]);
        mcalc(WegT, aggS, fB + 192, Sl, l, rb, mS);
        __syncthreads();
        // s4: GRU(m, h_ode)
        float az[4], ar[4], ani[4], anh[4];
        gruGemm(WiT, WhT, mS, hS, l, rb, fB, az, ar, ani, anh);
#pragma unroll
        for (int j = 0; j < 4; ++j) {
            float z = sigm(az[j]);
            float r = sigm(ar[j]);
            float nn = tanh_(ani[j] + r * anh[j]);
            h[j] = (1.f - z) * nn + z * ho[j];
        }
        __syncthreads();
        // s5: stage h_new, decode
#pragma unroll
        for (int j = 0; j < 4; ++j) hS[(rb + 4*j) * 64 + l] = f2bf(h[j]);
        __syncthreads();
        decodeStore(WdT, hS, fB + 320, rg, cg, outp, staged, f32, base, t);
    }
}

// de-transpose staged output [t][row][c] -> d_out [row][c][t]
__global__ __launch_bounds__(256) void k_detrans(const u16* __restrict__ stage,
                                                 const int* __restrict__ flag,
                                                 void* __restrict__ out) {
    __shared__ u16 lt[8 * CT_];   // 38,400 B
    int f32 = *flag;
    int tid = threadIdx.x;
    int base = blockIdx.x * 8;
    int r = tid >> 4, c = tid & 15;
    for (int t = 0; t < T_; ++t) {
        if (tid < 128)
            lt[r * CT_ + c * T_ + t] = stage[((size_t)t * NV_ + base + r) * C_ + c];
    }
    __syncthreads();
    size_t ob = (size_t)base * CT_;
    if (f32) {
        float* o = (float*)out;
        for (int i = tid; i < 8 * CT_; i += 256) o[ob + i] = bf2f(lt[i]);
    } else {
        u16* o = (u16*)out;
        for (int i = tid; i < 8 * CT_; i += 256) o[ob + i] = lt[i];
    }
}

// ---------------------------------------------------------------------------
extern "C" void kernel_launch(void* const* d_in, const int* in_sizes, int n_in,
                              void* d_out, int out_size, void* d_ws, size_t ws_size,
                              hipStream_t stream) {
    const void* x      = d_in[0];
    const int*  ei     = (const int*)d_in[1];
    const void* eattr  = d_in[2];
    const void* W_enc  = d_in[3];
    const void* b_enc  = d_in[4];
    const void* W_gd   = d_in[5];
    const void* gd_Wi  = d_in[6];
    const void* gd_Wh  = d_in[7];
    const void* gd_b   = d_in[8];
    const void* W_dom1 = d_in[9];
    const void* b_dom1 = d_in[10];
    const void* W_dom2 = d_in[11];
    const void* b_dom2 = d_in[12];
    const void* ode_W1 = d_in[13];
    const void* ode_b1 = d_in[14];
    const void* ode_W2 = d_in[15];
    const void* ode_b2 = d_in[16];
    const void* W_gc   = d_in[17];
    const void* gc_Wi  = d_in[18];
    const void* gc_Wh  = d_in[19];
    const void* gc_b   = d_in[20];
    const void* W_dec  = d_in[21];
    const void* b_dec  = d_in[22];

    char* ws = (char*)d_ws;
    u16*   aggT    = (u16*)  (ws + OFF_AGGT);
    int*   counts  = (int*)  (ws + OFF_COUNTS);
    float* S       = (float*)(ws + OFF_S);
    int*   row_ptr = (int*)  (ws + OFF_RP);
    int*   cursor  = (int*)  (ws + OFF_CUR);
    int*   col_src = (int*)  (ws + OFF_CSRC);
    float* col_att = (float*)(ws + OFF_CATT);
    u16*   wegA    = (u16*)  (ws + OFF_WEGA);
    u16*   wegB    = (u16*)  (ws + OFF_WEGB);
    float* begA    = (float*)(ws + OFF_BEGA);
    float* begB    = (float*)(ws + OFF_BEGB);
    int*   flag    = (int*)  (ws + OFF_FLAG);
    u16*   stage   = (u16*)  (ws + OFF_STAGE);

    int staged = (ws_size >= NEED_STAGE) ? 1 : 0;
    void* mega_out = staged ? (void*)stage : d_out;

    // allow >64KB dynamic LDS (no-op where not required); idempotent per call
    (void)hipFuncSetAttribute((const void*)k_mega,
                              hipFuncAttributeMaxDynamicSharedMemorySize, LDS_MEGA);

    hipLaunchKernelGGL(k_detect, dim3(1), dim3(256), 0, stream, (const u16*)x, flag);
    hipMemsetAsync(ws + OFF_COUNTS, 0, 16384, stream);  // counts + S
    hipLaunchKernelGGL(k_count, dim3(E_ / 256), dim3(256), 0, stream,
                       ei, eattr, flag, counts, S);
    hipLaunchKernelGGL(k_scan, dim3(1), dim3(256), 0, stream,
                       counts, row_ptr, cursor);
    hipLaunchKernelGGL(k_fill, dim3(E_ / 256), dim3(256), 0, stream,
                       ei, eattr, flag, cursor, col_src, col_att);
    hipLaunchKernelGGL(k_wprep, dim3(1), dim3(256), 0, stream,
                       W_enc, b_enc, W_gd, W_gc, flag, wegA, wegB, begA, begB);
    hipLaunchKernelGGL(k_agg, dim3(N_ * V_ / 4), dim3(256), 0, stream,
                       x, flag, row_ptr, col_src, col_att, aggT);
    hipLaunchKernelGGL(k_mega, dim3(NV_ / 16), dim3(256), LDS_MEGA, stream,
                       x, aggT, S, flag, W_enc, b_enc, gd_Wi, gd_Wh, gd_b,
                       W_dom1, b_dom1, W_dom2, b_dom2,
                       ode_W1, ode_b1, ode_W2, ode_b2,
                       gc_Wi, gc_Wh, gc_b, W_dec, b_dec,
                       wegA, wegB, begA, begB, mega_out, staged);
    if (staged)
        hipLaunchKernelGGL(k_detrans, dim3(NV_ / 8), dim3(256), 0, stream,
                           stage, flag, d_out);
}